// Round 3
// baseline (30893.765 us; speedup 1.0000x reference)
//
#include <hip/hip_runtime.h>
#include <math.h>

#define NDIM 4096
#define NR   4095        // rounds = N-1 (rotating positions)
#define NPAIRS 2048      // N/2 tables
#define CB   4           // columns per workgroup slice (state fits 128 VGPRs)
#define NTHREADS 256
#define TPT  8           // tables per thread (NPAIRS / NTHREADS)

// Precompute (c, s) per (round, table); bake in the orientation sign:
// table k at round r holds players a=(r+k)%NR (top) and b=(r-k)%NR (bottom,
// or 4095 fixed for k=0). Reference rotates (i,j)=(min,max) with
// U[i]=c*Ui-s*Uj, U[j]=s*Ui+c*Uj. If top==j the update is equivalent to
// negating s. top>bottom iff 0<k<=r<NR-k.
__global__ void cs_precompute(const float* __restrict__ thetas,
                              const int* __restrict__ round_theta,
                              float2* __restrict__ cs, int total) {
    int idx = blockIdx.x * blockDim.x + threadIdx.x;
    if (idx >= total) return;
    int r = idx / NPAIRS;
    int k = idx - r * NPAIRS;
    float th = thetas[round_theta[idx]];
    float s, c;
    sincosf(th, &s, &c);
    if (k > 0 && k <= r && r < NR - k) s = -s;
    cs[idx] = make_float2(c, s);
}

// Register-systolic circle method. Seats: top[g]=position g (g=0..2047),
// bottom[g]=position 4095-g (g>=1), bottom[0]=fixed player 4095.
// Each round: rotate each table (top[g],bot[g]) then shift ring by -1:
//   top[g] <- na(g+1); top[2047] <- nb(2047)
//   bot[g] <- nb(g-1) (g>=2); bot[1] <- na(0); bot[0] <- nb(0) (fixed seat)
// Thread t owns tables 8t..8t+7; only na(table 8t) and nb(table 8t+7) cross
// threads (shfl by 1 lane; LDS double-buffer at wave boundaries).
template<bool USE_CS>
__global__ __launch_bounds__(NTHREADS, 4)
void rotmat_systolic(const float2* __restrict__ cs,
                     const float* __restrict__ thetas,
                     float* __restrict__ out) {
    __shared__ float naBuf[2][4][CB];   // written by lane0 of each wave
    __shared__ float nbBuf[2][4][CB];   // written by lane63 of each wave

    const int tid  = threadIdx.x;
    const int lane = tid & 63;
    const int wave = tid >> 6;
    const int col0 = blockIdx.x * CB;

    float top[TPT][CB], bot[TPT][CB];
    // round 0: position q holds player q
#pragma unroll
    for (int u = 0; u < TPT; ++u) {
        int g = tid * TPT + u;
        int rowT = g;
        int rowB = (g == 0) ? (NDIM - 1) : (NR - g);
#pragma unroll
        for (int c = 0; c < CB; ++c) {
            top[u][c] = (rowT == col0 + c) ? 1.f : 0.f;
            bot[u][c] = (rowB == col0 + c) ? 1.f : 0.f;
        }
    }

    float2 csCur[TPT], csNext[TPT];
    if (USE_CS) {
        const float4* p = (const float4*)(cs + tid * TPT);
#pragma unroll
        for (int q = 0; q < TPT / 2; ++q) {
            float4 v = p[q];
            csCur[2 * q]     = make_float2(v.x, v.y);
            csCur[2 * q + 1] = make_float2(v.z, v.w);
        }
    }

    for (int r = 0; r < NR; ++r) {
        if (USE_CS && (r + 1 < NR)) {
            const float4* p =
                (const float4*)(cs + (size_t)(r + 1) * NPAIRS + tid * TPT);
#pragma unroll
            for (int q = 0; q < TPT / 2; ++q) {
                float4 v = p[q];
                csNext[2 * q]     = make_float2(v.x, v.y);
                csNext[2 * q + 1] = make_float2(v.z, v.w);
            }
        }

        float na0[CB], carry[CB];
#pragma unroll
        for (int u = 0; u < TPT; ++u) {
            float c_, s_;
            if (USE_CS) {
                c_ = csCur[u].x; s_ = csCur[u].y;
            } else {
                int g = tid * TPT + u;
                int aP = r + g; if (aP >= NR) aP -= NR;
                int bP;
                if (g == 0) bP = NDIM - 1;
                else { bP = r - g; if (bP < 0) bP += NR; }
                int i = aP < bP ? aP : bP;
                int j = aP < bP ? bP : aP;
                int t = i * NDIM - (i * (i + 1)) / 2 + (j - i - 1);
                float th = thetas[t];
                float s, c;
                sincosf(th, &s, &c);
                c_ = c; s_ = (aP < bP) ? s : -s;
            }
            float na[CB], nb[CB];
#pragma unroll
            for (int c = 0; c < CB; ++c) {
                float a = top[u][c], b = bot[u][c];
                na[c] = c_ * a - s_ * b;
                nb[c] = s_ * a + c_ * b;
            }
            if (u == 0) {
#pragma unroll
                for (int c = 0; c < CB; ++c) { na0[c] = na[c]; carry[c] = nb[c]; }
            } else {
#pragma unroll
                for (int c = 0; c < CB; ++c) {
                    top[u - 1][c] = na[c];     // top shifts left
                    bot[u][c]     = carry[c];  // bottom shifts right
                    carry[c]      = nb[c];
                }
            }
        }
        // carry = nb(table 8t+7); na0 = na(table 8t)
        float t7[CB], b0[CB];
#pragma unroll
        for (int c = 0; c < CB; ++c) {
            t7[c] = __shfl_down(na0[c], 1);   // from lane+1: its na0
            b0[c] = __shfl_up(carry[c], 1);   // from lane-1: its nb7
        }
        const int pb = r & 1;
        if (lane == 0) {
#pragma unroll
            for (int c = 0; c < CB; ++c) naBuf[pb][wave][c] = na0[c];
        }
        if (lane == 63) {
#pragma unroll
            for (int c = 0; c < CB; ++c) nbBuf[pb][wave][c] = carry[c];
        }
        __syncthreads();
        if (lane == 63) {
            if (wave < 3) {
#pragma unroll
                for (int c = 0; c < CB; ++c) t7[c] = naBuf[pb][wave + 1][c];
            } else {
                // global thread 255: top[2047] <- own nb(2047)
#pragma unroll
                for (int c = 0; c < CB; ++c) t7[c] = carry[c];
            }
        }
        if (lane == 0 && wave > 0) {
#pragma unroll
            for (int c = 0; c < CB; ++c) b0[c] = nbBuf[pb][wave - 1][c];
        }
#pragma unroll
        for (int c = 0; c < CB; ++c) top[TPT - 1][c] = t7[c];
        if (tid == 0) {
            // bot[1] currently holds nb(0): fixed seat keeps it; bot[1] <- na(0)
#pragma unroll
            for (int c = 0; c < CB; ++c) { bot[0][c] = bot[1][c]; bot[1][c] = na0[c]; }
        } else {
#pragma unroll
            for (int c = 0; c < CB; ++c) bot[0][c] = b0[c];
        }
        if (USE_CS) {
#pragma unroll
            for (int u = 0; u < TPT; ++u) csCur[u] = csNext[u];
        }
    }

    // After NR shifts, position q holds player q again:
    // top[g] = row g; bot[g] = row 4095-g (g>=1); bot[0] = row 4095.
#pragma unroll
    for (int u = 0; u < TPT; ++u) {
        int g = tid * TPT + u;
        int rowT = g;
        int rowB = (g == 0) ? (NDIM - 1) : (NR - g);
        float4* oT = (float4*)&out[(size_t)rowT * NDIM + col0];
        oT[0] = make_float4(top[u][0], top[u][1], top[u][2], top[u][3]);
        float4* oB = (float4*)&out[(size_t)rowB * NDIM + col0];
        oB[0] = make_float4(bot[u][0], bot[u][1], bot[u][2], bot[u][3]);
    }
}

extern "C" void kernel_launch(void* const* d_in, const int* in_sizes, int n_in,
                              void* d_out, int out_size, void* d_ws, size_t ws_size,
                              hipStream_t stream) {
    const float* thetas      = (const float*)d_in[0];
    const int*   round_theta = (const int*)d_in[3];
    float*       out         = (float*)d_out;

    const int total = NR * NPAIRS;
    const size_t need = (size_t)total * sizeof(float2);

    if (ws_size >= need) {
        float2* cs = (float2*)d_ws;
        cs_precompute<<<(total + 255) / 256, 256, 0, stream>>>(
            thetas, round_theta, cs, total);
        rotmat_systolic<true><<<NDIM / CB, NTHREADS, 0, stream>>>(cs, thetas, out);
    } else {
        rotmat_systolic<false><<<NDIM / CB, NTHREADS, 0, stream>>>(nullptr, thetas, out);
    }
}

// Round 4
// 6583.389 us; speedup vs baseline: 4.6927x; 4.6927x over previous
//
#include <hip/hip_runtime.h>
#include <math.h>

#define NDIM 4096
#define NR   4095        // rounds = N-1 (rotating positions)
#define NPAIRS 2048      // N/2 tables
#define CB   4           // columns per workgroup slice
#define NTHREADS 256
#define TPT  8           // tables per thread (NPAIRS / NTHREADS)

// Precompute (c, s) per (round, table); bake in the orientation sign:
// table k at round r holds players a=(r+k)%NR (top) and b=(r-k)%NR (bottom,
// or 4095 fixed for k=0). Reference rotates (i,j)=(min,max) with
// U[i]=c*Ui-s*Uj, U[j]=s*Ui+c*Uj. If top==j the update is equivalent to
// negating s. top>bottom iff 0<k<=r<NR-k.
__global__ void cs_precompute(const float* __restrict__ thetas,
                              const int* __restrict__ round_theta,
                              float2* __restrict__ cs, int total) {
    int idx = blockIdx.x * blockDim.x + threadIdx.x;
    if (idx >= total) return;
    int r = idx / NPAIRS;
    int k = idx - r * NPAIRS;
    float th = thetas[round_theta[idx]];
    float s, c;
    sincosf(th, &s, &c);
    if (k > 0 && k <= r && r < NR - k) s = -s;
    cs[idx] = make_float2(c, s);
}

// Register-systolic circle method. Seats: top[g]=position g (g=0..2047),
// bottom[g]=position 4095-g (g>=1), bottom[0]=fixed player 4095.
// Each round: rotate each table (top[g],bot[g]) then shift ring by -1:
//   top[g] <- na(g+1); top[2047] <- nb(2047)
//   bot[g] <- nb(g-1) (g>=2); bot[1] <- na(0); bot[0] <- nb(0) (fixed seat)
// Thread t owns tables 8t..8t+7; only na(table 8t) and nb(table 8t+7) cross
// threads (shfl by 1 lane; LDS double-buffer at wave boundaries).
// NOTE: __launch_bounds__ 2nd arg = min waves/EU = register CEILING.
// (256,4) forced a 128-reg budget -> 148 GB of scratch spill (round 3).
// (256,2) gives a 256-reg budget; ~130-float state fits in arch VGPRs.
template<bool USE_CS>
__global__ __launch_bounds__(NTHREADS, 2)
void rotmat_systolic(const float2* __restrict__ cs,
                     const float* __restrict__ thetas,
                     float* __restrict__ out) {
    __shared__ float naBuf[2][4][CB];   // written by lane0 of each wave
    __shared__ float nbBuf[2][4][CB];   // written by lane63 of each wave

    const int tid  = threadIdx.x;
    const int lane = tid & 63;
    const int wave = tid >> 6;
    const int col0 = blockIdx.x * CB;

    float top[TPT][CB], bot[TPT][CB];
    // round 0: position q holds player q
#pragma unroll
    for (int u = 0; u < TPT; ++u) {
        int g = tid * TPT + u;
        int rowT = g;
        int rowB = (g == 0) ? (NDIM - 1) : (NR - g);
#pragma unroll
        for (int c = 0; c < CB; ++c) {
            top[u][c] = (rowT == col0 + c) ? 1.f : 0.f;
            bot[u][c] = (rowB == col0 + c) ? 1.f : 0.f;
        }
    }

    float2 csCur[TPT], csNext[TPT];
    if (USE_CS) {
        const float4* p = (const float4*)(cs + tid * TPT);
#pragma unroll
        for (int q = 0; q < TPT / 2; ++q) {
            float4 v = p[q];
            csCur[2 * q]     = make_float2(v.x, v.y);
            csCur[2 * q + 1] = make_float2(v.z, v.w);
        }
    }

    for (int r = 0; r < NR; ++r) {
        if (USE_CS && (r + 1 < NR)) {
            const float4* p =
                (const float4*)(cs + (size_t)(r + 1) * NPAIRS + tid * TPT);
#pragma unroll
            for (int q = 0; q < TPT / 2; ++q) {
                float4 v = p[q];
                csNext[2 * q]     = make_float2(v.x, v.y);
                csNext[2 * q + 1] = make_float2(v.z, v.w);
            }
        }

        float na0[CB], carry[CB];
#pragma unroll
        for (int u = 0; u < TPT; ++u) {
            float c_, s_;
            if (USE_CS) {
                c_ = csCur[u].x; s_ = csCur[u].y;
            } else {
                int g = tid * TPT + u;
                int aP = r + g; if (aP >= NR) aP -= NR;
                int bP;
                if (g == 0) bP = NDIM - 1;
                else { bP = r - g; if (bP < 0) bP += NR; }
                int i = aP < bP ? aP : bP;
                int j = aP < bP ? bP : aP;
                int t = i * NDIM - (i * (i + 1)) / 2 + (j - i - 1);
                float th = thetas[t];
                float s, c;
                sincosf(th, &s, &c);
                c_ = c; s_ = (aP < bP) ? s : -s;
            }
            float na[CB], nb[CB];
#pragma unroll
            for (int c = 0; c < CB; ++c) {
                float a = top[u][c], b = bot[u][c];
                na[c] = c_ * a - s_ * b;
                nb[c] = s_ * a + c_ * b;
            }
            if (u == 0) {
#pragma unroll
                for (int c = 0; c < CB; ++c) { na0[c] = na[c]; carry[c] = nb[c]; }
            } else {
#pragma unroll
                for (int c = 0; c < CB; ++c) {
                    top[u - 1][c] = na[c];     // top shifts left
                    bot[u][c]     = carry[c];  // bottom shifts right
                    carry[c]      = nb[c];
                }
            }
        }
        // carry = nb(table 8t+7); na0 = na(table 8t)
        float t7[CB], b0[CB];
#pragma unroll
        for (int c = 0; c < CB; ++c) {
            t7[c] = __shfl_down(na0[c], 1);   // from lane+1: its na0
            b0[c] = __shfl_up(carry[c], 1);   // from lane-1: its nb7
        }
        const int pb = r & 1;
        if (lane == 0) {
#pragma unroll
            for (int c = 0; c < CB; ++c) naBuf[pb][wave][c] = na0[c];
        }
        if (lane == 63) {
#pragma unroll
            for (int c = 0; c < CB; ++c) nbBuf[pb][wave][c] = carry[c];
        }
        __syncthreads();
        if (lane == 63) {
            if (wave < 3) {
#pragma unroll
                for (int c = 0; c < CB; ++c) t7[c] = naBuf[pb][wave + 1][c];
            } else {
                // global thread 255: top[2047] <- own nb(2047)
#pragma unroll
                for (int c = 0; c < CB; ++c) t7[c] = carry[c];
            }
        }
        if (lane == 0 && wave > 0) {
#pragma unroll
            for (int c = 0; c < CB; ++c) b0[c] = nbBuf[pb][wave - 1][c];
        }
#pragma unroll
        for (int c = 0; c < CB; ++c) top[TPT - 1][c] = t7[c];
        if (tid == 0) {
            // bot[1] currently holds nb(0): fixed seat keeps it; bot[1] <- na(0)
#pragma unroll
            for (int c = 0; c < CB; ++c) { bot[0][c] = bot[1][c]; bot[1][c] = na0[c]; }
        } else {
#pragma unroll
            for (int c = 0; c < CB; ++c) bot[0][c] = b0[c];
        }
        if (USE_CS) {
#pragma unroll
            for (int u = 0; u < TPT; ++u) csCur[u] = csNext[u];
        }
    }

    // After NR shifts, position q holds player q again:
    // top[g] = row g; bot[g] = row 4095-g (g>=1); bot[0] = row 4095.
#pragma unroll
    for (int u = 0; u < TPT; ++u) {
        int g = tid * TPT + u;
        int rowT = g;
        int rowB = (g == 0) ? (NDIM - 1) : (NR - g);
        float4* oT = (float4*)&out[(size_t)rowT * NDIM + col0];
        oT[0] = make_float4(top[u][0], top[u][1], top[u][2], top[u][3]);
        float4* oB = (float4*)&out[(size_t)rowB * NDIM + col0];
        oB[0] = make_float4(bot[u][0], bot[u][1], bot[u][2], bot[u][3]);
    }
}

extern "C" void kernel_launch(void* const* d_in, const int* in_sizes, int n_in,
                              void* d_out, int out_size, void* d_ws, size_t ws_size,
                              hipStream_t stream) {
    const float* thetas      = (const float*)d_in[0];
    const int*   round_theta = (const int*)d_in[3];
    float*       out         = (float*)d_out;

    const int total = NR * NPAIRS;
    const size_t need = (size_t)total * sizeof(float2);

    if (ws_size >= need) {
        float2* cs = (float2*)d_ws;
        cs_precompute<<<(total + 255) / 256, 256, 0, stream>>>(
            thetas, round_theta, cs, total);
        rotmat_systolic<true><<<NDIM / CB, NTHREADS, 0, stream>>>(cs, thetas, out);
    } else {
        rotmat_systolic<false><<<NDIM / CB, NTHREADS, 0, stream>>>(nullptr, thetas, out);
    }
}